// Round 14
// baseline (112.073 us; speedup 1.0000x reference)
//
#include <hip/hip_runtime.h>
#include <math.h>

#define BB 64
#define NN 8192
#define TOTAL_W 9356

typedef _Float16 f16x4 __attribute__((ext_vector_type(4)));
typedef float f32x4 __attribute__((ext_vector_type(4)));
typedef float f32x2 __attribute__((ext_vector_type(2)));
typedef unsigned int u32x2 __attribute__((ext_vector_type(2)));

#define L2E 1.44269504088896340736f
#define LN2 0.6931471805599453f

// ---- ws layout (bytes, per b) ----
#define WS_FILM 0        // film2: [4 l][16 quad][{bias4,wsc4,bsc4,wsh4}] prescaled = 4096
#define WS_A1   4096     // A-tiles L1: [m][t][lane] f16x4 = 8192 (unscaled: L2E*LN2=1)
#define WS_A2   12288    // A-tiles L2 = 8192
#define WS_A0   20480    // A0 tile image [4 m][64 lane] f16x4, scaled by L2E = 2048
#define WS_A3   22528    // A3 tile image [4 t][64 lane] f16x4, scaled by LN2 = 2048
#define WSB     24576

// ---- LDS layout (bytes): verbatim copy of ws[0..20480) ----
#define FILM2_OFF 0
#define A1_OFF    4096
#define A2_OFF    12288
#define LDS_BYTES 20480   // 8 blocks/CU (8*20480 = 163840 exactly)

#if __has_builtin(__builtin_amdgcn_mfma_f32_16x16x16_f16)
#define MFMAK16(a, b, c) __builtin_amdgcn_mfma_f32_16x16x16_f16(a, b, c, 0, 0, 0)
#else
#define MFMAK16(a, b, c) __builtin_amdgcn_mfma_f32_16x16x16f16(a, b, c, 0, 0, 0)
#endif
#define EXP2 __builtin_amdgcn_exp2f
#define LOG2 __builtin_amdgcn_logf
#define RCPF __builtin_amdgcn_rcpf

__device__ __forceinline__ f32x2 pfma(f32x2 a, f32x2 b, f32x2 c) {
  return __builtin_elementwise_fma(a, b, c);
}

__device__ __forceinline__ const f32x4* film_base(const unsigned char* smem, int l, int qd) {
  return (const f32x4*)(smem + FILM2_OFF + ((l * 16 + qd) << 6));
}

// FiLM (+softplus, log2-domain) on a D-quad; acc includes (prescaled) bias.
// acc = L2E*pre; returns h~ = log2(1+2^(L2E*v)) packed f16x4 (= next B operand).
template<bool SP>
__device__ __forceinline__ f16x4 film_quad(f32x4 acc, float ctx,
                                           f32x4 wscq, f32x4 bscq, f32x4 wshq) {
  f32x2 ctx2 = {ctx, ctx};
  f32x2 one = {1.f, 1.f};
  f32x2 z0 = pfma(ctx2, (f32x2){wscq.x, wscq.y}, (f32x2){bscq.x, bscq.y});
  f32x2 z1 = pfma(ctx2, (f32x2){wscq.z, wscq.w}, (f32x2){bscq.z, bscq.w});
  f32x2 d0 = {EXP2(-z0.x), EXP2(-z0.y)};  d0 += one;
  f32x2 d1 = {EXP2(-z1.x), EXP2(-z1.y)};  d1 += one;
  f32x2 s0 = {RCPF(d0.x), RCPF(d0.y)};
  f32x2 s1 = {RCPF(d1.x), RCPF(d1.y)};
  f32x2 v0 = pfma(ctx2, (f32x2){wshq.x, wshq.y}, s0 * (f32x2){acc.x, acc.y});
  f32x2 v1 = pfma(ctx2, (f32x2){wshq.z, wshq.w}, s1 * (f32x2){acc.z, acc.w});
  if (SP) {  // h~ = log2(1 + 2^v~)
    f32x2 u0 = {EXP2(v0.x), EXP2(v0.y)};  u0 += one;
    f32x2 u1 = {EXP2(v1.x), EXP2(v1.y)};  u1 += one;
    v0 = (f32x2){LOG2(u0.x), LOG2(u0.y)};
    v1 = (f32x2){LOG2(u1.x), LOG2(u1.y)};
  }
  auto p01 = __builtin_amdgcn_cvt_pkrtz(v0.x, v0.y);
  auto p23 = __builtin_amdgcn_cvt_pkrtz(v1.x, v1.y);
  u32x2 w;
  w.x = __builtin_bit_cast(unsigned int, p01);
  w.y = __builtin_bit_cast(unsigned int, p23);
  return __builtin_bit_cast(f16x4, w);
}

__device__ __forceinline__ f16x4 a_tile(const unsigned char* smem, int aoff,
                                        int m, int t, int lane) {
  return *(const f16x4*)(smem + aoff + (((m * 4 + t) * 64 + lane) << 3));
}

// ============ prep kernel: one block per b, builds ws images ============
__global__ __launch_bounds__(512)
void ode_prep_kernel(const float* __restrict__ tnw, unsigned char* __restrict__ ws) {
  const int b = blockIdx.x;
  const int tid = threadIdx.x;
  const float* __restrict__ wb = tnw + (size_t)b * TOTAL_W;
  unsigned char* __restrict__ wsb = ws + (size_t)b * WSB;

  // film2 params; layer l: bias@bo, wsc@bo+d, bsc@bo+2d, wsh@bo+3d
  // Prescale: wsc,bsc by L2E (all l); bias,wsh by L2E for l<3 (log2-domain fold).
  if (tid < 64) {
    const int biaso[4] = {192, 4544, 8896, 9344};
    const int dim[4] = {64, 64, 64, 3};
#pragma unroll
    for (int l = 0; l < 4; ++l) {
      float bv = 0.f, wscv = 0.f, bscv = 0.f, wshv = 0.f;
      if (tid < dim[l]) {
        int bo = biaso[l], d = dim[l];
        float bs = (l < 3) ? L2E : 1.0f;
        bv = wb[bo + tid] * bs;
        wscv = wb[bo + d + tid] * L2E;
        bscv = wb[bo + 2 * d + tid] * L2E;
        wshv = wb[bo + 3 * d + tid] * bs;
      }
      float* f2 = (float*)(wsb + WS_FILM + ((l * 16 + (tid >> 2)) << 6)) + (tid & 3);
      f2[0] = bv;
      f2[4] = wscv;
      f2[8] = bscv;
      f2[12] = wshv;
    }
  }
  // A-tiles L1/L2 (A = W^T, 16x16), UNSCALED (L2E*LN2 = 1 folds away)
#pragma unroll
  for (int L = 0; L < 2; ++L) {
    const int woff = L ? 4800 : 448;
    unsigned char* dst = wsb + (L ? WS_A2 : WS_A1);
#pragma unroll
    for (int it = 0; it < 2; ++it) {
      int idx = tid + it * 512;          // < 1024
      int lane = idx & 63;
      int tile = idx >> 6;               // m*4 + t
      int m = tile >> 2, t = tile & 3;
      int f_out = 16 * m + (lane & 15);
      int f_in0 = 16 * t + 4 * (lane >> 4);
      f16x4 h;
#pragma unroll
      for (int i = 0; i < 4; ++i) h[i] = (_Float16)wb[woff + (f_in0 + i) * 64 + f_out];
      *(f16x4*)(dst + idx * 8) = h;
    }
  }
  // A0 tile image [m][lane], scaled by L2E
  if (tid < 256) {
    int m = tid >> 6;
    int lane = tid & 63;
    int kg = lane >> 4, row = lane & 15;
    f16x4 h = {0, 0, 0, 0};
    if (kg == 0) {
#pragma unroll
      for (int i = 0; i < 3; ++i) h[i] = (_Float16)(wb[i * 64 + 16 * m + row] * L2E);
    }
    *(f16x4*)(wsb + WS_A0 + tid * 8) = h;
  }
  // A3 tile image [t][lane], scaled by LN2 (consumes log2-domain h~)
  if (tid < 256) {
    int t = tid >> 6;
    int lane = tid & 63;
    int kg = lane >> 4, row = lane & 15;
    f16x4 h = {0, 0, 0, 0};
    if (row < 3) {
#pragma unroll
      for (int i = 0; i < 4; ++i)
        h[i] = (_Float16)(wb[9152 + (16 * t + 4 * kg + i) * 3 + row] * LN2);
    }
    *(f16x4*)(wsb + WS_A3 + tid * 8) = h;
  }
}

// ============ main kernel: 128 pts/block, 2 groups/wave, 8 waves/SIMD ============
__global__ __launch_bounds__(256, 8)
void ode_hypernet_kernel(const float* __restrict__ context,
                         const float* __restrict__ y,
                         const unsigned char* __restrict__ ws,
                         float* __restrict__ out) {
  __shared__ __align__(16) unsigned char smem[LDS_BYTES];
  const int b = blockIdx.y;
  const int tid = threadIdx.x;
  const unsigned char* __restrict__ wsb = ws + (size_t)b * WSB;

  const int lane = tid & 63;
  const int wid = tid >> 6;
  const int g = lane >> 4;
  const int col = lane & 15;

  // ---------- staging: linear coalesced copy of film2+A1+A2 (20 KB) ----------
#pragma unroll
  for (int it = 0; it < 5; ++it) {
    int i = tid + it * 256;  // i < 1280
    *(f32x4*)(smem + i * 16) = *(const f32x4*)(wsb + i * 16);
  }
  f16x4 A0r[4], A3r[4];
#pragma unroll
  for (int m = 0; m < 4; ++m)
    A0r[m] = *(const f16x4*)(wsb + WS_A0 + ((m * 64 + lane) << 3));
#pragma unroll
  for (int t = 0; t < 4; ++t)
    A3r[t] = *(const f16x4*)(wsb + WS_A3 + ((t * 64 + lane) << 3));
  __syncthreads();

  // ---------- per-wave main: 2 point-groups ----------
  const int pt0 = wid * 32 + col;  // 0..127
  const int nb = blockIdx.x * 128;
  const size_t cb = (size_t)b * NN;

  float ctxs[2];
  f16x4 By[2];
#pragma unroll
  for (int k = 0; k < 2; ++k) {  // group k -> point nb + pt0 + k*16
    int n = nb + pt0 + k * 16;
    ctxs[k] = context[cb + n];
    const float* yp = y + (cb + n) * 3;
    f16x4 v = {0, 0, 0, 0};
    if (g == 0) {
      v[0] = (_Float16)yp[0];
      v[1] = (_Float16)yp[1];
      v[2] = (_Float16)yp[2];
    }
    By[k] = v;
  }

  f16x4 Bc[2][4], Bd[2][4];  // [group][tile]

  // ----- layer 0 (3 -> 64) -----
#pragma unroll
  for (int m = 0; m < 4; ++m) {
    const f32x4* fb = film_base(smem, 0, 4 * m + g);
    f32x4 biasq = fb[0], wscq = fb[1], bscq = fb[2], wshq = fb[3];
#pragma unroll
    for (int k = 0; k < 2; ++k) {
      f32x4 c = biasq;
      c = MFMAK16(A0r[m], By[k], c);
      Bc[k][m] = film_quad<true>(c, ctxs[k], wscq, bscq, wshq);
    }
  }

  // ----- layer 1 (64 -> 64): Bc -> Bd -----
#pragma unroll
  for (int m = 0; m < 4; ++m) {
    const f32x4* fb = film_base(smem, 1, 4 * m + g);
    f32x4 biasq = fb[0], wscq = fb[1], bscq = fb[2], wshq = fb[3];
    f16x4 a[4];
#pragma unroll
    for (int t = 0; t < 4; ++t) a[t] = a_tile(smem, A1_OFF, m, t, lane);
#pragma unroll
    for (int k = 0; k < 2; ++k) {
      f32x4 c = biasq;
#pragma unroll
      for (int t = 0; t < 4; ++t) c = MFMAK16(a[t], Bc[k][t], c);
      Bd[k][m] = film_quad<true>(c, ctxs[k], wscq, bscq, wshq);
    }
  }

  // ----- layer 2 (64 -> 64): Bd -> Bc -----
#pragma unroll
  for (int m = 0; m < 4; ++m) {
    const f32x4* fb = film_base(smem, 2, 4 * m + g);
    f32x4 biasq = fb[0], wscq = fb[1], bscq = fb[2], wshq = fb[3];
    f16x4 a[4];
#pragma unroll
    for (int t = 0; t < 4; ++t) a[t] = a_tile(smem, A2_OFF, m, t, lane);
#pragma unroll
    for (int k = 0; k < 2; ++k) {
      f32x4 c = biasq;
#pragma unroll
      for (int t = 0; t < 4; ++t) c = MFMAK16(a[t], Bd[k][t], c);
      Bc[k][m] = film_quad<true>(c, ctxs[k], wscq, bscq, wshq);
    }
  }

  // ----- layer 3 (64 -> 3): A from regs (LN2-prescaled), FiLM only -----
  {
    const f32x4* fb = film_base(smem, 3, g);
    f32x4 biasq = fb[0], wscq = fb[1], bscq = fb[2], wshq = fb[3];
#pragma unroll
    for (int k = 0; k < 2; ++k) {
      f32x4 c = biasq;
#pragma unroll
      for (int t = 0; t < 4; ++t) c = MFMAK16(A3r[t], Bc[k][t], c);
      if (g == 0) {
        int n = nb + pt0 + k * 16;
        float ctx = ctxs[k];
#pragma unroll
        for (int j = 0; j < 3; ++j) {
          float z = fmaf(ctx, wscq[j], bscq[j]);
          float s = RCPF(1.0f + EXP2(-z));
          float v = fmaf(ctx, wshq[j], s * c[j]);
          out[((size_t)b * NN + n) * 3 + j] = v;
        }
      }
    }
  }
}

extern "C" void kernel_launch(void* const* d_in, const int* in_sizes, int n_in,
                              void* d_out, int out_size, void* d_ws, size_t ws_size,
                              hipStream_t stream) {
  const float* context = (const float*)d_in[0];  // (64, 8192)
  const float* y       = (const float*)d_in[1];  // (64, 8192, 3)
  const float* tnw     = (const float*)d_in[2];  // (64, 9356)
  float* out           = (float*)d_out;          // (64, 8192, 3)
  unsigned char* ws    = (unsigned char*)d_ws;   // needs 64*24576 = 1,572,864 B

  ode_prep_kernel<<<dim3(BB, 1, 1), dim3(512, 1, 1), 0, stream>>>(tnw, ws);
  dim3 grid(NN / 128, BB, 1);  // 4096 blocks, 128 points each
  dim3 block(256, 1, 1);
  ode_hypernet_kernel<<<grid, block, 0, stream>>>(context, y, ws, out);
}

// Round 15
// 57.257 us; speedup vs baseline: 1.9574x; 1.9574x over previous
//
#include <hip/hip_runtime.h>
#include <math.h>

#define BB 64
#define NN 8192
#define TOTAL_W 9356

typedef _Float16 f16x4 __attribute__((ext_vector_type(4)));
typedef float f32x4 __attribute__((ext_vector_type(4)));
typedef float f32x2 __attribute__((ext_vector_type(2)));
typedef unsigned int u32x2 __attribute__((ext_vector_type(2)));

#define L2E 1.44269504088896340736f
#define LN2 0.6931471805599453f

// ---- ws layout (bytes, per b) ----
#define WS_FILM 0        // film2: [4 l][16 quad][{bias4,wsc4,bsc4,wsh4}] prescaled = 4096
#define WS_A1   4096     // A-tiles L1: [m][t][lane] f16x4 = 8192 (unscaled: L2E*LN2=1)
#define WS_A2   12288    // A-tiles L2 = 8192
#define WS_A0   20480    // A0 tile image [4 m][64 lane] f16x4, scaled by L2E = 2048
#define WS_A3   22528    // A3 tile image [4 t][64 lane] f16x4, scaled by LN2 = 2048
#define WSB     24576

// ---- LDS layout (bytes): verbatim copy of ws[0..20480) ----
#define FILM2_OFF 0
#define A1_OFF    4096
#define A2_OFF    12288
#define LDS_BYTES 20480   // 8 blocks/CU possible

#if __has_builtin(__builtin_amdgcn_mfma_f32_16x16x16_f16)
#define MFMAK16(a, b, c) __builtin_amdgcn_mfma_f32_16x16x16_f16(a, b, c, 0, 0, 0)
#else
#define MFMAK16(a, b, c) __builtin_amdgcn_mfma_f32_16x16x16f16(a, b, c, 0, 0, 0)
#endif
#define EXP2 __builtin_amdgcn_exp2f
#define LOG2 __builtin_amdgcn_logf
#define RCPF __builtin_amdgcn_rcpf

__device__ __forceinline__ f32x2 pfma(f32x2 a, f32x2 b, f32x2 c) {
  return __builtin_elementwise_fma(a, b, c);
}

__device__ __forceinline__ const f32x4* film_base(const unsigned char* smem, int l, int qd) {
  return (const f32x4*)(smem + FILM2_OFF + ((l * 16 + qd) << 6));
}

// FiLM (+softplus, log2-domain) on a D-quad; acc includes (prescaled) bias.
template<bool SP>
__device__ __forceinline__ f16x4 film_quad(f32x4 acc, float ctx,
                                           f32x4 wscq, f32x4 bscq, f32x4 wshq) {
  f32x2 ctx2 = {ctx, ctx};
  f32x2 one = {1.f, 1.f};
  f32x2 z0 = pfma(ctx2, (f32x2){wscq.x, wscq.y}, (f32x2){bscq.x, bscq.y});
  f32x2 z1 = pfma(ctx2, (f32x2){wscq.z, wscq.w}, (f32x2){bscq.z, bscq.w});
  f32x2 d0 = {EXP2(-z0.x), EXP2(-z0.y)};  d0 += one;
  f32x2 d1 = {EXP2(-z1.x), EXP2(-z1.y)};  d1 += one;
  f32x2 s0 = {RCPF(d0.x), RCPF(d0.y)};
  f32x2 s1 = {RCPF(d1.x), RCPF(d1.y)};
  f32x2 v0 = pfma(ctx2, (f32x2){wshq.x, wshq.y}, s0 * (f32x2){acc.x, acc.y});
  f32x2 v1 = pfma(ctx2, (f32x2){wshq.z, wshq.w}, s1 * (f32x2){acc.z, acc.w});
  if (SP) {  // h~ = log2(1 + 2^v~)
    f32x2 u0 = {EXP2(v0.x), EXP2(v0.y)};  u0 += one;
    f32x2 u1 = {EXP2(v1.x), EXP2(v1.y)};  u1 += one;
    v0 = (f32x2){LOG2(u0.x), LOG2(u0.y)};
    v1 = (f32x2){LOG2(u1.x), LOG2(u1.y)};
  }
  auto p01 = __builtin_amdgcn_cvt_pkrtz(v0.x, v0.y);
  auto p23 = __builtin_amdgcn_cvt_pkrtz(v1.x, v1.y);
  u32x2 w;
  w.x = __builtin_bit_cast(unsigned int, p01);
  w.y = __builtin_bit_cast(unsigned int, p23);
  return __builtin_bit_cast(f16x4, w);
}

__device__ __forceinline__ f16x4 a_tile(const unsigned char* smem, int aoff,
                                        int m, int t, int lane) {
  return *(const f16x4*)(smem + aoff + (((m * 4 + t) * 64 + lane) << 3));
}

// ============ prep kernel: one block per b, builds ws images ============
__global__ __launch_bounds__(512)
void ode_prep_kernel(const float* __restrict__ tnw, unsigned char* __restrict__ ws) {
  const int b = blockIdx.x;
  const int tid = threadIdx.x;
  const float* __restrict__ wb = tnw + (size_t)b * TOTAL_W;
  unsigned char* __restrict__ wsb = ws + (size_t)b * WSB;

  if (tid < 64) {
    const int biaso[4] = {192, 4544, 8896, 9344};
    const int dim[4] = {64, 64, 64, 3};
#pragma unroll
    for (int l = 0; l < 4; ++l) {
      float bv = 0.f, wscv = 0.f, bscv = 0.f, wshv = 0.f;
      if (tid < dim[l]) {
        int bo = biaso[l], d = dim[l];
        float bs = (l < 3) ? L2E : 1.0f;
        bv = wb[bo + tid] * bs;
        wscv = wb[bo + d + tid] * L2E;
        bscv = wb[bo + 2 * d + tid] * L2E;
        wshv = wb[bo + 3 * d + tid] * bs;
      }
      float* f2 = (float*)(wsb + WS_FILM + ((l * 16 + (tid >> 2)) << 6)) + (tid & 3);
      f2[0] = bv;
      f2[4] = wscv;
      f2[8] = bscv;
      f2[12] = wshv;
    }
  }
  // A-tiles L1/L2 (A = W^T, 16x16), UNSCALED (L2E*LN2 = 1 folds away)
#pragma unroll
  for (int L = 0; L < 2; ++L) {
    const int woff = L ? 4800 : 448;
    unsigned char* dst = wsb + (L ? WS_A2 : WS_A1);
#pragma unroll
    for (int it = 0; it < 2; ++it) {
      int idx = tid + it * 512;          // < 1024
      int lane = idx & 63;
      int tile = idx >> 6;               // m*4 + t
      int m = tile >> 2, t = tile & 3;
      int f_out = 16 * m + (lane & 15);
      int f_in0 = 16 * t + 4 * (lane >> 4);
      f16x4 h;
#pragma unroll
      for (int i = 0; i < 4; ++i) h[i] = (_Float16)wb[woff + (f_in0 + i) * 64 + f_out];
      *(f16x4*)(dst + idx * 8) = h;
    }
  }
  // A0 tile image [m][lane], scaled by L2E
  if (tid < 256) {
    int m = tid >> 6;
    int lane = tid & 63;
    int kg = lane >> 4, row = lane & 15;
    f16x4 h = {0, 0, 0, 0};
    if (kg == 0) {
#pragma unroll
      for (int i = 0; i < 3; ++i) h[i] = (_Float16)(wb[i * 64 + 16 * m + row] * L2E);
    }
    *(f16x4*)(wsb + WS_A0 + tid * 8) = h;
  }
  // A3 tile image [t][lane], scaled by LN2 (consumes log2-domain h~)
  if (tid < 256) {
    int t = tid >> 6;
    int lane = tid & 63;
    int kg = lane >> 4, row = lane & 15;
    f16x4 h = {0, 0, 0, 0};
    if (row < 3) {
#pragma unroll
      for (int i = 0; i < 4; ++i)
        h[i] = (_Float16)(wb[9152 + (16 * t + 4 * kg + i) * 3 + row] * LN2);
    }
    *(f16x4*)(wsb + WS_A3 + tid * 8) = h;
  }
}

// ============ main kernel: 128 pts/block, 2 groups/wave, 6 waves/SIMD ============
__global__ __launch_bounds__(256, 6)
void ode_hypernet_kernel(const float* __restrict__ context,
                         const float* __restrict__ y,
                         const unsigned char* __restrict__ ws,
                         float* __restrict__ out) {
  __shared__ __align__(16) unsigned char smem[LDS_BYTES];
  const int b = blockIdx.y;
  const int tid = threadIdx.x;
  const unsigned char* __restrict__ wsb = ws + (size_t)b * WSB;

  const int lane = tid & 63;
  const int wid = tid >> 6;
  const int g = lane >> 4;
  const int col = lane & 15;

  // ---------- staging: linear coalesced copy of film2+A1+A2 (20 KB) ----------
#pragma unroll
  for (int it = 0; it < 5; ++it) {
    int i = tid + it * 256;  // i < 1280
    *(f32x4*)(smem + i * 16) = *(const f32x4*)(wsb + i * 16);
  }
  f16x4 A0r[4], A3r[4];
#pragma unroll
  for (int m = 0; m < 4; ++m)
    A0r[m] = *(const f16x4*)(wsb + WS_A0 + ((m * 64 + lane) << 3));
#pragma unroll
  for (int t = 0; t < 4; ++t)
    A3r[t] = *(const f16x4*)(wsb + WS_A3 + ((t * 64 + lane) << 3));
  __syncthreads();

  // ---------- per-wave main: 2 point-groups ----------
  const int pt0 = wid * 32 + col;  // 0..127
  const int nb = blockIdx.x * 128;
  const size_t cb = (size_t)b * NN;

  float ctxs[2];
  f16x4 By[2];
#pragma unroll
  for (int k = 0; k < 2; ++k) {  // group k -> point nb + pt0 + k*16
    int n = nb + pt0 + k * 16;
    ctxs[k] = context[cb + n];
    const float* yp = y + (cb + n) * 3;
    f16x4 v = {0, 0, 0, 0};
    if (g == 0) {
      v[0] = (_Float16)yp[0];
      v[1] = (_Float16)yp[1];
      v[2] = (_Float16)yp[2];
    }
    By[k] = v;
  }

  f16x4 Bc[2][4], Bd[2][4];  // [group][tile]

  // ----- layer 0 (3 -> 64) -----
#pragma unroll
  for (int m = 0; m < 4; ++m) {
    const f32x4* fb = film_base(smem, 0, 4 * m + g);
    f32x4 biasq = fb[0], wscq = fb[1], bscq = fb[2], wshq = fb[3];
#pragma unroll
    for (int k = 0; k < 2; ++k) {
      f32x4 c = biasq;
      c = MFMAK16(A0r[m], By[k], c);
      Bc[k][m] = film_quad<true>(c, ctxs[k], wscq, bscq, wshq);
    }
  }

  // ----- layer 1 (64 -> 64): Bc -> Bd -----
#pragma unroll
  for (int m = 0; m < 4; ++m) {
    const f32x4* fb = film_base(smem, 1, 4 * m + g);
    f32x4 biasq = fb[0], wscq = fb[1], bscq = fb[2], wshq = fb[3];
    f16x4 a[4];
#pragma unroll
    for (int t = 0; t < 4; ++t) a[t] = a_tile(smem, A1_OFF, m, t, lane);
#pragma unroll
    for (int k = 0; k < 2; ++k) {
      f32x4 c = biasq;
#pragma unroll
      for (int t = 0; t < 4; ++t) c = MFMAK16(a[t], Bc[k][t], c);
      Bd[k][m] = film_quad<true>(c, ctxs[k], wscq, bscq, wshq);
    }
  }

  // ----- layer 2 (64 -> 64): Bd -> Bc -----
#pragma unroll
  for (int m = 0; m < 4; ++m) {
    const f32x4* fb = film_base(smem, 2, 4 * m + g);
    f32x4 biasq = fb[0], wscq = fb[1], bscq = fb[2], wshq = fb[3];
    f16x4 a[4];
#pragma unroll
    for (int t = 0; t < 4; ++t) a[t] = a_tile(smem, A2_OFF, m, t, lane);
#pragma unroll
    for (int k = 0; k < 2; ++k) {
      f32x4 c = biasq;
#pragma unroll
      for (int t = 0; t < 4; ++t) c = MFMAK16(a[t], Bd[k][t], c);
      Bc[k][m] = film_quad<true>(c, ctxs[k], wscq, bscq, wshq);
    }
  }

  // ----- layer 3 (64 -> 3): A from regs (LN2-prescaled), FiLM only -----
  {
    const f32x4* fb = film_base(smem, 3, g);
    f32x4 biasq = fb[0], wscq = fb[1], bscq = fb[2], wshq = fb[3];
#pragma unroll
    for (int k = 0; k < 2; ++k) {
      f32x4 c = biasq;
#pragma unroll
      for (int t = 0; t < 4; ++t) c = MFMAK16(A3r[t], Bc[k][t], c);
      if (g == 0) {
        int n = nb + pt0 + k * 16;
        float ctx = ctxs[k];
#pragma unroll
        for (int j = 0; j < 3; ++j) {
          float z = fmaf(ctx, wscq[j], bscq[j]);
          float s = RCPF(1.0f + EXP2(-z));
          float v = fmaf(ctx, wshq[j], s * c[j]);
          out[((size_t)b * NN + n) * 3 + j] = v;
        }
      }
    }
  }
}

extern "C" void kernel_launch(void* const* d_in, const int* in_sizes, int n_in,
                              void* d_out, int out_size, void* d_ws, size_t ws_size,
                              hipStream_t stream) {
  const float* context = (const float*)d_in[0];  // (64, 8192)
  const float* y       = (const float*)d_in[1];  // (64, 8192, 3)
  const float* tnw     = (const float*)d_in[2];  // (64, 9356)
  float* out           = (float*)d_out;          // (64, 8192, 3)
  unsigned char* ws    = (unsigned char*)d_ws;   // needs 64*24576 = 1,572,864 B

  ode_prep_kernel<<<dim3(BB, 1, 1), dim3(512, 1, 1), 0, stream>>>(tnw, ws);
  dim3 grid(NN / 128, BB, 1);  // 4096 blocks, 128 points each
  dim3 block(256, 1, 1);
  ode_hypernet_kernel<<<grid, block, 0, stream>>>(context, y, ws, out);
}